// Round 7
// baseline (316.772 us; speedup 1.0000x reference)
//
#include <hip/hip_runtime.h>
#include <hip/hip_bf16.h>

// DecoderConv: weighted conv1d (B=8, Cin=Cout=256, L=16384, K=9) + BatchNorm(train) + ReLU
// Round-7: stage-time weighting. Per kk, threads weight reg-resident raw x (from xT)
// and write pre-weighted bf16 tile Xw[2] with conflict-free b128 writes; B-frags are
// direct ds_read_b128 (zero VALU between LDS and MFMA). A via global_load_lds (r6).
// setprio(1) around MFMA cluster. 1 barrier/kk. Optional bf16 y intermediate.

typedef float        f32x4  __attribute__((ext_vector_type(4)));
typedef float        f32x16 __attribute__((ext_vector_type(16)));
typedef short        bf16x8 __attribute__((ext_vector_type(8)));
typedef unsigned int u32x4  __attribute__((ext_vector_type(4)));

#define LLEN 16384

__device__ __forceinline__ unsigned short bf16bits(float a) {
  return __builtin_bit_cast(unsigned short, __float2bfloat16(a));
}
__device__ __forceinline__ unsigned cvt_pk_bf16(float lo, float hi) {
  unsigned r;
  asm("v_cvt_pk_bf16_f32 %0, %1, %2" : "=v"(r) : "v"(lo), "v"(hi));
  return r;
}
__device__ __forceinline__ void gload16(const void* g, void* l) {
  __builtin_amdgcn_global_load_lds(
      (const __attribute__((address_space(1))) unsigned int*)g,
      (__attribute__((address_space(3))) unsigned int*)l, 16, 0, 0);
}
__device__ __forceinline__ float bflo(unsigned u) {
  return __builtin_bit_cast(float, u << 16);
}
__device__ __forceinline__ float bfhi(unsigned u) {
  return __builtin_bit_cast(float, u & 0xffff0000u);
}

// ================= k_prep =================
__global__ void k_prep(const float* __restrict__ cw,
                       unsigned short* __restrict__ A_r4,
                       unsigned short* __restrict__ A_gl,
                       float* __restrict__ sums, int big) {
  const int idx = blockIdx.x * 256 + threadIdx.x;  // 2304*256 = 256*256*9 exactly
  if (idx < 1024) sums[idx] = 0.0f;
  const int o   = idx / 2304;
  const int rem = idx - o * 2304;
  const int c   = rem / 9;
  const int kk  = rem - c * 9;
  const unsigned short bits = bf16bits(cw[idx]);
  A_r4[((size_t)kk * 256 + o) * 256 + c] = bits;
  if (big) {
    const int cc = c >> 6, c6 = c & 63;
    const int u = (c6 >> 3) ^ (o & 7);
    A_gl[(size_t)((kk * 4 + cc) << 14) + ((o * 8 + u) << 3) + (c6 & 7)] = bits;
  }
}

// ================= k_w =================
__global__ void k_w(const float* __restrict__ coords, float* __restrict__ wbuf) {
  const int gidx = blockIdx.x * 256 + threadIdx.x;  // = b*L + l
  const int b = gidx >> 14, l = gidx & (LLEN - 1);
  const float* cb = coords + (size_t)b * 3 * LLEN;
  const float c0 = cb[l], c1 = cb[LLEN + l], c2v = cb[2 * LLEN + l];
#pragma unroll
  for (int kk = 0; kk < 9; ++kk) {
    const int lc = l + kk - 4;
    float a0 = 0.f, a1 = 0.f, a2 = 0.f;
    if (lc >= 0 && lc < LLEN) { a0 = cb[lc]; a1 = cb[LLEN + lc]; a2 = cb[2 * LLEN + lc]; }
    const float d0 = a0 - c0, d1 = a1 - c1, d2 = a2 - c2v;
    wbuf[(((size_t)(b * 9 + kk)) << 14) + l] = __expf(-0.5f * (d0 * d0 + d1 * d1 + d2 * d2));
  }
}

// ================= k_xT: x -> bf16 xT[b][l][c], XOR swizzle baked (r6-proven) ======
__global__ void k_xT(const float* __restrict__ x, unsigned short* __restrict__ xT) {
  __shared__ unsigned short T[64][72];
  const int tid = threadIdx.x, bid = blockIdx.x;
  const int ct = bid & 3, lt = (bid >> 2) & 255, b = bid >> 10;
  const int l0 = lt << 6, c0 = ct << 6;
#pragma unroll
  for (int p = 0; p < 4; ++p) {
    const int cl = p * 16 + (tid >> 4), ll = (tid & 15) << 2;
    const f32x4 v = *reinterpret_cast<const f32x4*>(
        x + (((size_t)(b * 256 + c0 + cl)) << 14) + l0 + ll);
#pragma unroll
    for (int q = 0; q < 4; ++q) T[cl][ll + q] = bf16bits(v[q]);
  }
  __syncthreads();
#pragma unroll
  for (int pass = 0; pass < 2; ++pass) {
    const int n = tid + pass * 256;
    const int ll = n >> 3, u = n & 7;
    const int l = l0 + ll;
    const int gsl = (u ^ (l & 7)) << 3;
    u32x4 val;
#pragma unroll
    for (int q = 0; q < 4; ++q)
      val[q] = (unsigned)T[gsl + 2 * q][ll] | ((unsigned)T[gsl + 2 * q + 1][ll] << 16);
    *reinterpret_cast<u32x4*>(xT + (((size_t)((b << 14) + l)) << 8) + (ct << 6) + (u << 3)) = val;
  }
}

// ================= k_gemm_w =================
template <int YBF>
__global__ __launch_bounds__(512, 2) void k_gemm_w(
    const unsigned short* __restrict__ xT, const float* __restrict__ wbuf,
    const unsigned short* __restrict__ Agl, const float* __restrict__ convb,
    float* __restrict__ yf, unsigned short* __restrict__ ybf,
    float* __restrict__ sums) {
  __shared__ __align__(16) unsigned short Ash[2][16384];   // 32KB each, DMA target
  __shared__ __align__(16) unsigned short Xw[2][264 * 64]; // 33KB each, pre-weighted

  const int tid = threadIdx.x, lane = tid & 63, wv = tid >> 6;
  const int wm = wv >> 2, wn = wv & 3;          // 2x4 waves, wave tile 128o x 64l
  const int l31 = lane & 31, hi5 = lane >> 5;
  const int b = blockIdx.x >> 6, lt = blockIdx.x & 63, l0 = lt << 8;
  const int rbase = tid >> 3, uu = tid & 7;     // staging unit coords

  f32x16 acc[4][2];
#pragma unroll
  for (int i = 0; i < 4; ++i)
#pragma unroll
    for (int j = 0; j < 2; ++j) acc[i][j] = (f32x16)(0.0f);

  auto dmaA = [&](int ab, int kk, int cc) {
#pragma unroll
    for (int call = 0; call < 4; ++call) {
      const int n0 = ((call << 3) + wv) << 6;
      gload16(Agl + (((size_t)((kk << 2) + cc)) << 14) + (((size_t)(n0 + lane)) << 3),
              (char*)&Ash[ab][0] + n0 * 16);
    }
  };
  auto loadX = [&](int cc, int i) -> u32x4 {
    u32x4 v = {0u, 0u, 0u, 0u};
    if (i < 4 || tid < 64) {
      const int r = rbase + 64 * i;
      const int l = l0 - 4 + r;
      if (l >= 0 && l < LLEN)
        v = *reinterpret_cast<const u32x4*>(
            xT + (((size_t)((b << 14) + l)) << 8) + cc * 64 + uu * 8);
    }
    return v;
  };
  // weight unit i of xr with w[b][nkk] and write into Xw[xwb] (conflict-free b128)
  auto stage = [&](int xwb, int nkk, const u32x4 (&xr)[5]) {
    const float* wrow = wbuf + ((size_t)(b * 9 + nkk) << 14);
#pragma unroll
    for (int i = 0; i < 5; ++i) {
      if (i < 4 || tid < 64) {
        const int r = rbase + 64 * i;
        int lo_ = l0 + r - nkk;
        lo_ = lo_ < 0 ? 0 : (lo_ > LLEN - 1 ? LLEN - 1 : lo_);
        const float wv2 = wrow[lo_];
        u32x4 o4;
#pragma unroll
        for (int q = 0; q < 4; ++q)
          o4[q] = cvt_pk_bf16(bflo(xr[i][q]) * wv2, bfhi(xr[i][q]) * wv2);
        *reinterpret_cast<u32x4*>(
            reinterpret_cast<char*>(&Xw[xwb][0]) + r * 128 + ((uu ^ 4) << 4)) = o4;
      }
    }
  };

  // ---- prologue ----
  u32x4 xcur[5], xnext[5];
#pragma unroll
  for (int i = 0; i < 5; ++i) xcur[i] = loadX(0, i);
  dmaA(0, 0, 0);
  stage(0, 0, xcur);
  __syncthreads();

  int ab = 0, xwb = 0;
#pragma unroll 1
  for (int cc = 0; cc < 4; ++cc) {
#pragma unroll 1
    for (int kk = 0; kk < 9; ++kk) {
      const bool last = (cc == 3) && (kk == 8);
      const int nkk = (kk == 8) ? 0 : kk + 1;
      const int ncc = (kk == 8) ? cc + 1 : cc;
      if (!last) dmaA(ab ^ 1, nkk, ncc);
      // next-chunk x reg loads, one unit per kk=4..8 (landed well before kk=8 stage)
      if (cc < 3 && kk >= 4) xnext[kk - 4] = loadX(cc + 1, kk - 4);

      // ---- compute: 4 ks, direct frag reads + MFMA (setprio) ----
      const char* AshB = (const char*)&Ash[ab][0];
      const char* XwB  = (const char*)&Xw[xwb][0];
#pragma unroll
      for (int ks = 0; ks < 4; ++ks) {
        const int g = (ks << 1) + hi5;
        bf16x8 bfr[2];
#pragma unroll
        for (int nt = 0; nt < 2; ++nt) {
          const int R = wn * 64 + nt * 32 + l31 + kk;
          bfr[nt] = *reinterpret_cast<const bf16x8*>(
              XwB + R * 128 + ((g ^ (R & 7)) << 4));
        }
        bf16x8 afr[4];
#pragma unroll
        for (int mt = 0; mt < 4; ++mt) {
          const int o = wm * 128 + mt * 32 + l31;
          afr[mt] = *reinterpret_cast<const bf16x8*>(
              AshB + o * 128 + ((g ^ (l31 & 7)) << 4));
        }
        __builtin_amdgcn_s_setprio(1);
#pragma unroll
        for (int mt = 0; mt < 4; ++mt)
#pragma unroll
          for (int nt = 0; nt < 2; ++nt)
            acc[mt][nt] = __builtin_amdgcn_mfma_f32_32x32x16_bf16(afr[mt], bfr[nt],
                                                                  acc[mt][nt], 0, 0, 0);
        __builtin_amdgcn_s_setprio(0);
      }

      // ---- stage next tap's weighted tile ----
      if (!last) {
        if (kk < 8) stage(xwb ^ 1, nkk, xcur);
        else        stage(xwb ^ 1, 0, xnext);
      }
      __syncthreads();
      ab ^= 1; xwb ^= 1;
    }
    if (cc < 3) {
#pragma unroll
      for (int i = 0; i < 5; ++i) xcur[i] = xnext[i];
    }
  }

  // ---- epilogue: +conv_b, y store (f32 or bf16), per-channel sums ----
  // 32x32 C/D map (m74/m101): col = lane&31, row = (v&3) + 8*(v>>2) + 4*(lane>>5)
  float* red = reinterpret_cast<float*>(&Xw[0][0]);  // 512 floats
  red[tid] = 0.0f;
  __syncthreads();
#pragma unroll
  for (int mt = 0; mt < 4; ++mt) {
#pragma unroll
    for (int v = 0; v < 16; ++v) {
      const int o = wm * 128 + mt * 32 + (v & 3) + 8 * (v >> 2) + 4 * hi5;
      const float cb = convb[o];
      float s = 0.f, s2 = 0.f;
#pragma unroll
      for (int nt = 0; nt < 2; ++nt) {
        const int l = l0 + wn * 64 + nt * 32 + l31;
        const float yv = acc[mt][nt][v] + cb;
        const size_t idx = (((size_t)b * 256 + o) << 14) + l;
        if (YBF) ybf[idx] = bf16bits(yv);
        else     yf[idx] = yv;
        s += yv; s2 += yv * yv;
      }
#pragma unroll
      for (int d = 1; d < 32; d <<= 1) { s += __shfl_xor(s, d); s2 += __shfl_xor(s2, d); }
      if (l31 == 0) { atomicAdd(&red[o], s); atomicAdd(&red[o + 256], s2); }
    }
  }
  __syncthreads();
  atomicAdd(&sums[tid], red[tid]);
}

// ================= k_gemm_fb: r4 verbatim (proven PASS) for small-ws safety ========
__global__ __launch_bounds__(512, 2) void k_gemm_fb(
    const float* __restrict__ x, const float* __restrict__ wbuf,
    const unsigned short* __restrict__ Aperm, const float* __restrict__ convb,
    float* __restrict__ y, float* __restrict__ sums) {
  __shared__ __align__(16) unsigned short Ash[2][256 * 64];
  __shared__ __align__(16) unsigned short Xsh[2][264 * 72];

  const int tid  = threadIdx.x;
  const int lane = tid & 63, wv = tid >> 6;
  const int wm = wv >> 2, wn = wv & 3;
  const int hi = lane >> 4, lo16 = lane & 15;
  const int b  = blockIdx.x >> 6, lt = blockIdx.x & 63;
  const int l0 = lt << 8;
  const int nbase = wn * 64 + lo16;
  const int c = tid >> 3, rg = tid & 7;

  f32x4 acc[8][4];
#pragma unroll
  for (int i = 0; i < 8; ++i)
#pragma unroll
    for (int j = 0; j < 4; ++j) acc[i][j] = f32x4{0.f, 0.f, 0.f, 0.f};

  auto loadA = [&](int kk, int cc, u32x4 (&dst)[4]) {
#pragma unroll
    for (int p = 0; p < 4; ++p) {
      const int row = p * 64 + (tid >> 3);
      dst[p] = *reinterpret_cast<const u32x4*>(
          Aperm + ((size_t)kk * 256 + row) * 256 + cc * 64 + ((tid & 7) << 3));
    }
  };
  auto writeA = [&](int ab, const u32x4 (&src)[4]) {
#pragma unroll
    for (int p = 0; p < 4; ++p) {
      const int row  = p * 64 + (tid >> 3);
      const unsigned byte = (unsigned)(row * 128 + (((tid & 7) ^ (row & 7)) << 4));
      *reinterpret_cast<u32x4*>(reinterpret_cast<char*>(&Ash[ab][0]) + byte) = src[p];
    }
  };
  auto loadPiece = [&](int ncc, int i) -> f32x4 {
    const float* xrow = x + ((size_t)(b * 256 + ncc * 64 + c)) * LLEN;
    const int grp = rg + 8 * i;
    const int lx = l0 - 4 + grp * 4;
    f32x4 v = {0.f, 0.f, 0.f, 0.f};
    if (grp < 66 && lx >= 0 && lx <= LLEN - 4)
      v = *reinterpret_cast<const f32x4*>(xrow + lx);
    return v;
  };
  auto writePiece = [&](int xb, int i, const f32x4& v) {
    const int grp = rg + 8 * i;
    if (grp < 66) {
      unsigned short* base = &Xsh[xb][0] + (grp * 4) * 72 + c;
      base[0]   = bf16bits(v[0]);
      base[72]  = bf16bits(v[1]);
      base[144] = bf16bits(v[2]);
      base[216] = bf16bits(v[3]);
    }
  };

  {
    u32x4 a0[4];
    loadA(0, 0, a0);
    writeA(0, a0);
#pragma unroll
    for (int i = 0; i < 9; ++i) writePiece(0, i, loadPiece(0, i));
  }
  float wl[4];
#pragma unroll
  for (int nt = 0; nt < 4; ++nt)
    wl[nt] = wbuf[((size_t)(b * 9) << 14) + l0 + nbase + nt * 16];
  __syncthreads();

  int ab = 0;
  f32x4 xhold = {0.f, 0.f, 0.f, 0.f};

#pragma unroll 1
  for (int cc = 0; cc < 4; ++cc) {
    const int xb = cc & 1;
#pragma unroll 1
    for (int kk = 0; kk < 9; ++kk) {
      const int nkk = (kk == 8) ? 0 : kk + 1;
      const int ncc = (kk == 8) ? cc + 1 : cc;
      const bool has_next = (ncc < 4);

      u32x4 areg[4];
      if (has_next) loadA(nkk, ncc, areg);
      float wln[4] = {0.f, 0.f, 0.f, 0.f};
      if (has_next) {
#pragma unroll
        for (int nt = 0; nt < 4; ++nt)
          wln[nt] = wbuf[((size_t)(b * 9 + nkk) << 14) + l0 + nbase + nt * 16];
      }
      f32x4 xnew = {0.f, 0.f, 0.f, 0.f};
      if (cc < 3) xnew = loadPiece(cc + 1, kk);

      const char* AshB = reinterpret_cast<const char*>(&Ash[ab][0]);
      const char* XshB = reinterpret_cast<const char*>(&Xsh[xb][0]);
#pragma unroll
      for (int kb = 0; kb < 2; ++kb) {
        bf16x8 bfr[4];
#pragma unroll
        for (int nt = 0; nt < 4; ++nt) {
          const int r = nbase + nt * 16 + kk;
          const u32x4 xv = *reinterpret_cast<const u32x4*>(XshB + r * 144 + kb * 64 + hi * 16);
          const float wv2 = wl[nt];
          u32x4 o4;
#pragma unroll
          for (int q = 0; q < 4; ++q)
            o4[q] = cvt_pk_bf16(bflo(xv[q]) * wv2, bfhi(xv[q]) * wv2);
          bfr[nt] = __builtin_bit_cast(bf16x8, o4);
        }
#pragma unroll
        for (int mt = 0; mt < 8; ++mt) {
          const int orow = wm * 128 + mt * 16 + lo16;
          const unsigned aoff = (unsigned)(orow * 128 + (((kb * 4 + hi) ^ (orow & 7)) << 4));
          const bf16x8 af = *reinterpret_cast<const bf16x8*>(AshB + aoff);
#pragma unroll
          for (int nt = 0; nt < 4; ++nt)
            acc[mt][nt] = __builtin_amdgcn_mfma_f32_16x16x32_bf16(af, bfr[nt],
                                                                  acc[mt][nt], 0, 0, 0);
        }
      }

      if (cc < 3 && kk >= 1) writePiece(xb ^ 1, kk - 1, xhold);
      if (cc < 3 && kk == 8) writePiece(xb ^ 1, 8, xnew);
      if (has_next) writeA(ab ^ 1, areg);

      __syncthreads();
      ab ^= 1;
      xhold = xnew;
#pragma unroll
      for (int nt = 0; nt < 4; ++nt) wl[nt] = wln[nt];
    }
  }

  float* red = reinterpret_cast<float*>(&Ash[0][0]);
  red[tid] = 0.0f;
  __syncthreads();
#pragma unroll
  for (int mt = 0; mt < 8; ++mt) {
#pragma unroll
    for (int v = 0; v < 4; ++v) {
      const int o = wm * 128 + mt * 16 + hi * 4 + v;
      const float cb = convb[o];
      float s = 0.f, s2 = 0.f;
#pragma unroll
      for (int nt = 0; nt < 4; ++nt) {
        const int l = l0 + nbase + nt * 16;
        const float yv = acc[mt][nt][v] + cb;
        y[(((size_t)b * 256 + o) << 14) + l] = yv;
        s += yv; s2 += yv * yv;
      }
#pragma unroll
      for (int d = 1; d < 16; d <<= 1) { s += __shfl_xor(s, d); s2 += __shfl_xor(s2, d); }
      if (lo16 == 0) { atomicAdd(&red[o], s); atomicAdd(&red[o + 256], s2); }
    }
  }
  __syncthreads();
  atomicAdd(&sums[tid], red[tid]);
}

// ================= k_norm =================
template <int YBF>
__global__ void k_norm(const float* __restrict__ yf, const unsigned short* __restrict__ ybf,
                       float* __restrict__ out, const float* __restrict__ sums,
                       const float* __restrict__ gamma, const float* __restrict__ beta) {
  const size_t i0 = ((size_t)blockIdx.x * 256 + threadIdx.x) * 8;
  const int o = (int)((i0 >> 14) & 255);
  const float n = 131072.f;  // B*L
  const float mu = sums[o] / n;
  float var = sums[256 + o] / n - mu * mu;
  var = fmaxf(var, 0.f);
  const float sc = rsqrtf(var + 1e-5f) * gamma[o];
  const float bb = beta[o] - mu * sc;
  f32x4 v0, v1;
  if (YBF) {
    const u32x4 u = *reinterpret_cast<const u32x4*>(ybf + i0);
#pragma unroll
    for (int i = 0; i < 4; ++i) {
      const unsigned w = u[i];
      float a = bflo(w), c = bfhi(w);
      if (i < 2) { v0[2 * i] = a; v0[2 * i + 1] = c; }
      else       { v1[2 * (i - 2)] = a; v1[2 * (i - 2) + 1] = c; }
    }
  } else {
    v0 = *reinterpret_cast<const f32x4*>(yf + i0);
    v1 = *reinterpret_cast<const f32x4*>(yf + i0 + 4);
  }
#pragma unroll
  for (int i = 0; i < 4; ++i) {
    v0[i] = fmaxf(v0[i] * sc + bb, 0.f);
    v1[i] = fmaxf(v1[i] * sc + bb, 0.f);
  }
  *reinterpret_cast<f32x4*>(out + i0) = v0;
  *reinterpret_cast<f32x4*>(out + i0 + 4) = v1;
}

// ================= launch =================
extern "C" void kernel_launch(void* const* d_in, const int* in_sizes, int n_in,
                              void* d_out, int out_size, void* d_ws, size_t ws_size,
                              hipStream_t stream) {
  const float* x      = (const float*)d_in[0];
  const float* coords = (const float*)d_in[1];
  const float* conv_w = (const float*)d_in[2];
  const float* conv_b = (const float*)d_in[3];
  const float* gamma  = (const float*)d_in[4];
  const float* beta   = (const float*)d_in[5];
  float* out = (float*)d_out;

  // ws: stats 2KB | pad 2KB | wbuf 4.72MB | A_r4 1.18MB | A_gl 1.18MB | xT 67.1MB | ybf 67.1MB
  float* sums = (float*)d_ws;
  float* wbuf = (float*)((char*)d_ws + 4096);
  unsigned short* A_r4 = (unsigned short*)((char*)d_ws + 4096 + (size_t)8 * 9 * LLEN * 4);
  unsigned short* A_gl = A_r4 + 589824;
  unsigned short* xT   = A_gl + 589824;
  unsigned short* ybf  = xT + 33554432;
  const size_t need_big = 4096 + (size_t)8 * 9 * LLEN * 4 + 2 * 1179648ull + 67108864ull;
  const size_t need_ybf = need_big + 67108864ull;
  const int big  = (ws_size >= need_big) ? 1 : 0;
  const int ybfp = (ws_size >= need_ybf) ? 1 : 0;

  k_prep<<<2304, 256, 0, stream>>>(conv_w, A_r4, A_gl, sums, big);
  k_w<<<512, 256, 0, stream>>>(coords, wbuf);
  if (big) {
    k_xT<<<8192, 256, 0, stream>>>(x, xT);
    if (ybfp) {
      k_gemm_w<1><<<512, 512, 0, stream>>>(xT, wbuf, A_gl, conv_b, out, ybf, sums);
      k_norm<1><<<16384, 256, 0, stream>>>(out, ybf, out, sums, gamma, beta);
    } else {
      k_gemm_w<0><<<512, 512, 0, stream>>>(xT, wbuf, A_gl, conv_b, out, ybf, sums);
      k_norm<0><<<16384, 256, 0, stream>>>(out, ybf, out, sums, gamma, beta);
    }
  } else {
    k_gemm_fb<<<512, 512, 0, stream>>>(x, wbuf, A_r4, conv_b, out, sums);
    k_norm<0><<<16384, 256, 0, stream>>>(out, nullptr, out, sums, gamma, beta);
  }
}

// Round 8
// 254.392 us; speedup vs baseline: 1.2452x; 1.2452x over previous
//
#include <hip/hip_runtime.h>
#include <hip/hip_bf16.h>

// DecoderConv: weighted conv1d (B=8, Cin=Cout=256, L=16384, K=9) + BatchNorm(train) + ReLU
// Round-8: r6 DMA machinery + 16x16x32 MFMA (conflict-free frag reads at 128B-row XOR
// layouts; 32x32 spans 32 rows -> structural 4-way conflict, 16x16 spans 16 -> free).
// kb-halves hand-pipelined; w prefetched one kk ahead; y stored bf16 (k_norm<1>).

typedef float        f32x4  __attribute__((ext_vector_type(4)));
typedef short        bf16x8 __attribute__((ext_vector_type(8)));
typedef unsigned int u32x4  __attribute__((ext_vector_type(4)));

#define LLEN 16384

__device__ __forceinline__ unsigned short bf16bits(float a) {
  return __builtin_bit_cast(unsigned short, __float2bfloat16(a));
}
__device__ __forceinline__ unsigned cvt_pk_bf16(float lo, float hi) {
  unsigned r;
  asm("v_cvt_pk_bf16_f32 %0, %1, %2" : "=v"(r) : "v"(lo), "v"(hi));
  return r;
}
__device__ __forceinline__ void gload16(const void* g, void* l) {
  __builtin_amdgcn_global_load_lds(
      (const __attribute__((address_space(1))) unsigned int*)g,
      (__attribute__((address_space(3))) unsigned int*)l, 16, 0, 0);
}
__device__ __forceinline__ float bflo(unsigned u) {
  return __builtin_bit_cast(float, u << 16);
}
__device__ __forceinline__ float bfhi(unsigned u) {
  return __builtin_bit_cast(float, u & 0xffff0000u);
}

// ================= k_prep: A union (big: DMA-swizzled A_gl / small: A_r4) =========
__global__ void k_prep(const float* __restrict__ cw,
                       unsigned short* __restrict__ AU,
                       float* __restrict__ sums, int big) {
  const int idx = blockIdx.x * 256 + threadIdx.x;  // 2304*256 = 256*256*9 exactly
  if (idx < 1024) sums[idx] = 0.0f;                // stats(512) + zeros page(512)
  const int o   = idx / 2304;
  const int rem = idx - o * 2304;
  const int c   = rem / 9;
  const int kk  = rem - c * 9;
  const unsigned short bits = bf16bits(cw[idx]);
  if (big) {
    const int cc = c >> 6, c6 = c & 63;
    const int u = (c6 >> 3) ^ (o & 7);
    AU[(size_t)((kk * 4 + cc) << 14) + ((o * 8 + u) << 3) + (c6 & 7)] = bits;
  } else {
    AU[((size_t)kk * 256 + o) * 256 + c] = bits;
  }
}

// ================= k_w =================
__global__ void k_w(const float* __restrict__ coords, float* __restrict__ wbuf) {
  const int gidx = blockIdx.x * 256 + threadIdx.x;  // = b*L + l
  const int b = gidx >> 14, l = gidx & (LLEN - 1);
  const float* cb = coords + (size_t)b * 3 * LLEN;
  const float c0 = cb[l], c1 = cb[LLEN + l], c2v = cb[2 * LLEN + l];
#pragma unroll
  for (int kk = 0; kk < 9; ++kk) {
    const int lc = l + kk - 4;
    float a0 = 0.f, a1 = 0.f, a2 = 0.f;
    if (lc >= 0 && lc < LLEN) { a0 = cb[lc]; a1 = cb[LLEN + lc]; a2 = cb[2 * LLEN + lc]; }
    const float d0 = a0 - c0, d1 = a1 - c1, d2 = a2 - c2v;
    wbuf[(((size_t)(b * 9 + kk)) << 14) + l] = __expf(-0.5f * (d0 * d0 + d1 * d1 + d2 * d2));
  }
}

// ================= k_xT: x -> bf16 xT[b][l][c], XOR swizzle baked (r6-proven) ======
__global__ void k_xT(const float* __restrict__ x, unsigned short* __restrict__ xT) {
  __shared__ unsigned short T[64][72];
  const int tid = threadIdx.x, bid = blockIdx.x;
  const int ct = bid & 3, lt = (bid >> 2) & 255, b = bid >> 10;
  const int l0 = lt << 6, c0 = ct << 6;
#pragma unroll
  for (int p = 0; p < 4; ++p) {
    const int cl = p * 16 + (tid >> 4), ll = (tid & 15) << 2;
    const f32x4 v = *reinterpret_cast<const f32x4*>(
        x + (((size_t)(b * 256 + c0 + cl)) << 14) + l0 + ll);
#pragma unroll
    for (int q = 0; q < 4; ++q) T[cl][ll + q] = bf16bits(v[q]);
  }
  __syncthreads();
#pragma unroll
  for (int pass = 0; pass < 2; ++pass) {
    const int n = tid + pass * 256;
    const int ll = n >> 3, u = n & 7;
    const int l = l0 + ll;
    const int gsl = (u ^ (l & 7)) << 3;
    u32x4 val;
#pragma unroll
    for (int q = 0; q < 4; ++q)
      val[q] = (unsigned)T[gsl + 2 * q][ll] | ((unsigned)T[gsl + 2 * q + 1][ll] << 16);
    *reinterpret_cast<u32x4*>(xT + (((size_t)((b << 14) + l)) << 8) + (ct << 6) + (u << 3)) = val;
  }
}

// ================= k_gemm16: DMA staging + 16x16x32 conflict-free frag reads =======
template <int YBF>
__global__ __launch_bounds__(512, 2) void k_gemm16(
    const unsigned short* __restrict__ xT, const float* __restrict__ wbuf,
    const unsigned short* __restrict__ Agl, const float* __restrict__ convb,
    const unsigned short* __restrict__ zeros, float* __restrict__ yf,
    unsigned short* __restrict__ ybf, float* __restrict__ sums) {
  __shared__ __align__(16) unsigned short Ash[2][16384];  // 32KB each: [o][8 swz units]
  __shared__ __align__(16) unsigned short Xsh[2][17408];  // 34KB each: 272 rows x 128B

  const int tid = threadIdx.x, lane = tid & 63, wv = tid >> 6;
  const int wm = wv >> 2, wn = wv & 3;          // 2x4 waves, wave tile 128o x 64l
  const int hi = lane >> 4, lo16 = lane & 15;
  const int b = blockIdx.x >> 6, lt = blockIdx.x & 63, l0 = lt << 8;
  const int nbase = wn * 64 + lo16;

  f32x4 acc[8][4];
#pragma unroll
  for (int i = 0; i < 8; ++i)
#pragma unroll
    for (int j = 0; j < 4; ++j) acc[i][j] = f32x4{0.f, 0.f, 0.f, 0.f};

  auto dmaA = [&](int ab, int kk, int cc) {
#pragma unroll
    for (int call = 0; call < 4; ++call) {
      const int n0 = ((call << 3) + wv) << 6;   // wave-uniform LDS base unit
      gload16(Agl + (((size_t)((kk << 2) + cc)) << 14) + (((size_t)(n0 + lane)) << 3),
              (char*)&Ash[ab][0] + n0 * 16);
    }
  };
  auto dmaX = [&](int xb, int ncc, int slot) {
    const int id = (slot << 3) + wv;            // 0..39, valid < 34
    if (id < 34) {
      const int n0 = id << 6;
      const int n = n0 + lane;
      const int r = n >> 3, u = n & 7;
      const int lp = l0 - 4 + r;
      const unsigned short* src =
          (lp >= 0 && lp < LLEN)
              ? xT + (((size_t)((b << 14) + lp)) << 8) + (ncc << 6) + (u << 3)
              : zeros;
      gload16(src, (char*)&Xsh[xb][0] + n0 * 16);
    }
  };

  // ---- prologue ----
  dmaA(0, 0, 0);
#pragma unroll
  for (int s = 0; s < 5; ++s) dmaX(0, 0, s);
  float wl[4], wt[4];
#pragma unroll
  for (int nt = 0; nt < 4; ++nt)
    wl[nt] = wbuf[((size_t)(b * 9) << 14) + l0 + nbase + nt * 16];
  __syncthreads();

  int ab = 0;
#pragma unroll 1
  for (int cc = 0; cc < 4; ++cc) {
    const int xb = cc & 1;
    const char* XshB = (const char*)&Xsh[xb][0];
#pragma unroll 1
    for (int kk = 0; kk < 9; ++kk) {
      const bool last = (cc == 3) && (kk == 8);
      const int nkk = (kk == 8) ? 0 : kk + 1;
      const int ncc = (kk == 8) ? cc + 1 : cc;
      if (!last) {
        dmaA(ab ^ 1, nkk, ncc);
#pragma unroll
        for (int nt = 0; nt < 4; ++nt)
          wt[nt] = wbuf[((size_t)(b * 9 + nkk) << 14) + l0 + nbase + nt * 16];
      }
      if (cc < 3 && kk < 5) dmaX(xb ^ 1, cc + 1, kk);

      const char* AshB = (const char*)&Ash[ab][0];
      // ---- kb=0: raw B reads ----
      u32x4 xv0[4];
#pragma unroll
      for (int nt = 0; nt < 4; ++nt) {
        const int rr = nbase + nt * 16 + kk;
        xv0[nt] = *reinterpret_cast<const u32x4*>(
            XshB + rr * 128 + ((hi ^ ((rr + 4) & 7)) << 4));
      }
      // ---- kb=0: A frags ----
      bf16x8 a0[8];
#pragma unroll
      for (int mt = 0; mt < 8; ++mt) {
        const int o = wm * 128 + mt * 16 + lo16;  // o&7 == lo16&7
        a0[mt] = *reinterpret_cast<const bf16x8*>(
            AshB + o * 128 + ((hi ^ (lo16 & 7)) << 4));
      }
      // ---- kb=0: build B frags (apply gaussian w) ----
      bf16x8 b0[4];
#pragma unroll
      for (int nt = 0; nt < 4; ++nt) {
        u32x4 o4;
#pragma unroll
        for (int q = 0; q < 4; ++q)
          o4[q] = cvt_pk_bf16(bflo(xv0[nt][q]) * wl[nt], bfhi(xv0[nt][q]) * wl[nt]);
        b0[nt] = __builtin_bit_cast(bf16x8, o4);
      }
      // ---- kb=1: raw B reads issued before kb=0 MFMA cluster ----
      u32x4 xv1[4];
#pragma unroll
      for (int nt = 0; nt < 4; ++nt) {
        const int rr = nbase + nt * 16 + kk;
        xv1[nt] = *reinterpret_cast<const u32x4*>(
            XshB + rr * 128 + (((4 + hi) ^ ((rr + 4) & 7)) << 4));
      }
      // ---- kb=0 MFMA cluster ----
#pragma unroll
      for (int mt = 0; mt < 8; ++mt)
#pragma unroll
        for (int nt = 0; nt < 4; ++nt)
          acc[mt][nt] = __builtin_amdgcn_mfma_f32_16x16x32_bf16(a0[mt], b0[nt],
                                                                acc[mt][nt], 0, 0, 0);
      // ---- kb=1: A frags + build + MFMA ----
      bf16x8 a1[8];
#pragma unroll
      for (int mt = 0; mt < 8; ++mt) {
        const int o = wm * 128 + mt * 16 + lo16;
        a1[mt] = *reinterpret_cast<const bf16x8*>(
            AshB + o * 128 + (((4 + hi) ^ (lo16 & 7)) << 4));
      }
      bf16x8 b1[4];
#pragma unroll
      for (int nt = 0; nt < 4; ++nt) {
        u32x4 o4;
#pragma unroll
        for (int q = 0; q < 4; ++q)
          o4[q] = cvt_pk_bf16(bflo(xv1[nt][q]) * wl[nt], bfhi(xv1[nt][q]) * wl[nt]);
        b1[nt] = __builtin_bit_cast(bf16x8, o4);
      }
#pragma unroll
      for (int mt = 0; mt < 8; ++mt)
#pragma unroll
        for (int nt = 0; nt < 4; ++nt)
          acc[mt][nt] = __builtin_amdgcn_mfma_f32_16x16x32_bf16(a1[mt], b1[nt],
                                                                acc[mt][nt], 0, 0, 0);

      __syncthreads();
      ab ^= 1;
#pragma unroll
      for (int nt = 0; nt < 4; ++nt) wl[nt] = wt[nt];
    }
  }

  // ---- epilogue (r4-verified 16x16 C/D map): +conv_b, y store, channel sums ----
  float* red = reinterpret_cast<float*>(&Xsh[0][0]);  // 512 floats
  red[tid] = 0.0f;
  __syncthreads();
#pragma unroll
  for (int mt = 0; mt < 8; ++mt) {
#pragma unroll
    for (int v = 0; v < 4; ++v) {
      const int o = wm * 128 + mt * 16 + hi * 4 + v;  // row = hi*4 + reg
      const float cb = convb[o];
      float s = 0.f, s2 = 0.f;
#pragma unroll
      for (int nt = 0; nt < 4; ++nt) {
        const int l = l0 + nbase + nt * 16;           // col = lo16
        const float yv = acc[mt][nt][v] + cb;
        const size_t idx = (((size_t)b * 256 + o) << 14) + l;
        if (YBF) ybf[idx] = bf16bits(yv);
        else     yf[idx] = yv;
        s += yv; s2 += yv * yv;
      }
#pragma unroll
      for (int d = 1; d < 16; d <<= 1) { s += __shfl_xor(s, d); s2 += __shfl_xor(s2, d); }
      if (lo16 == 0) { atomicAdd(&red[o], s); atomicAdd(&red[o + 256], s2); }
    }
  }
  __syncthreads();
  atomicAdd(&sums[tid], red[tid]);
}

// ================= k_gemm_fb: r4 verbatim (proven PASS) for small-ws safety ========
__global__ __launch_bounds__(512, 2) void k_gemm_fb(
    const float* __restrict__ x, const float* __restrict__ wbuf,
    const unsigned short* __restrict__ Aperm, const float* __restrict__ convb,
    float* __restrict__ y, float* __restrict__ sums) {
  __shared__ __align__(16) unsigned short Ash[2][256 * 64];
  __shared__ __align__(16) unsigned short Xsh[2][264 * 72];

  const int tid  = threadIdx.x;
  const int lane = tid & 63, wv = tid >> 6;
  const int wm = wv >> 2, wn = wv & 3;
  const int hi = lane >> 4, lo16 = lane & 15;
  const int b  = blockIdx.x >> 6, lt = blockIdx.x & 63;
  const int l0 = lt << 8;
  const int nbase = wn * 64 + lo16;
  const int c = tid >> 3, rg = tid & 7;

  f32x4 acc[8][4];
#pragma unroll
  for (int i = 0; i < 8; ++i)
#pragma unroll
    for (int j = 0; j < 4; ++j) acc[i][j] = f32x4{0.f, 0.f, 0.f, 0.f};

  auto loadA = [&](int kk, int cc, u32x4 (&dst)[4]) {
#pragma unroll
    for (int p = 0; p < 4; ++p) {
      const int row = p * 64 + (tid >> 3);
      dst[p] = *reinterpret_cast<const u32x4*>(
          Aperm + ((size_t)kk * 256 + row) * 256 + cc * 64 + ((tid & 7) << 3));
    }
  };
  auto writeA = [&](int ab, const u32x4 (&src)[4]) {
#pragma unroll
    for (int p = 0; p < 4; ++p) {
      const int row  = p * 64 + (tid >> 3);
      const unsigned byte = (unsigned)(row * 128 + (((tid & 7) ^ (row & 7)) << 4));
      *reinterpret_cast<u32x4*>(reinterpret_cast<char*>(&Ash[ab][0]) + byte) = src[p];
    }
  };
  auto loadPiece = [&](int ncc, int i) -> f32x4 {
    const float* xrow = x + ((size_t)(b * 256 + ncc * 64 + c)) * LLEN;
    const int grp = rg + 8 * i;
    const int lx = l0 - 4 + grp * 4;
    f32x4 v = {0.f, 0.f, 0.f, 0.f};
    if (grp < 66 && lx >= 0 && lx <= LLEN - 4)
      v = *reinterpret_cast<const f32x4*>(xrow + lx);
    return v;
  };
  auto writePiece = [&](int xb, int i, const f32x4& v) {
    const int grp = rg + 8 * i;
    if (grp < 66) {
      unsigned short* base = &Xsh[xb][0] + (grp * 4) * 72 + c;
      base[0]   = bf16bits(v[0]);
      base[72]  = bf16bits(v[1]);
      base[144] = bf16bits(v[2]);
      base[216] = bf16bits(v[3]);
    }
  };

  {
    u32x4 a0[4];
    loadA(0, 0, a0);
    writeA(0, a0);
#pragma unroll
    for (int i = 0; i < 9; ++i) writePiece(0, i, loadPiece(0, i));
  }
  float wl[4];
#pragma unroll
  for (int nt = 0; nt < 4; ++nt)
    wl[nt] = wbuf[((size_t)(b * 9) << 14) + l0 + nbase + nt * 16];
  __syncthreads();

  int ab = 0;
  f32x4 xhold = {0.f, 0.f, 0.f, 0.f};

#pragma unroll 1
  for (int cc = 0; cc < 4; ++cc) {
    const int xb = cc & 1;
#pragma unroll 1
    for (int kk = 0; kk < 9; ++kk) {
      const int nkk = (kk == 8) ? 0 : kk + 1;
      const int ncc = (kk == 8) ? cc + 1 : cc;
      const bool has_next = (ncc < 4);

      u32x4 areg[4];
      if (has_next) loadA(nkk, ncc, areg);
      float wln[4] = {0.f, 0.f, 0.f, 0.f};
      if (has_next) {
#pragma unroll
        for (int nt = 0; nt < 4; ++nt)
          wln[nt] = wbuf[((size_t)(b * 9 + nkk) << 14) + l0 + nbase + nt * 16];
      }
      f32x4 xnew = {0.f, 0.f, 0.f, 0.f};
      if (cc < 3) xnew = loadPiece(cc + 1, kk);

      const char* AshB = reinterpret_cast<const char*>(&Ash[ab][0]);
      const char* XshB = reinterpret_cast<const char*>(&Xsh[xb][0]);
#pragma unroll
      for (int kb = 0; kb < 2; ++kb) {
        bf16x8 bfr[4];
#pragma unroll
        for (int nt = 0; nt < 4; ++nt) {
          const int r = nbase + nt * 16 + kk;
          const u32x4 xv = *reinterpret_cast<const u32x4*>(XshB + r * 144 + kb * 64 + hi * 16);
          u32x4 o4;
#pragma unroll
          for (int q = 0; q < 4; ++q)
            o4[q] = cvt_pk_bf16(bflo(xv[q]) * wl[nt], bfhi(xv[q]) * wl[nt]);
          bfr[nt] = __builtin_bit_cast(bf16x8, o4);
        }
#pragma unroll
        for (int mt = 0; mt < 8; ++mt) {
          const int orow = wm * 128 + mt * 16 + lo16;
          const unsigned aoff = (unsigned)(orow * 128 + (((kb * 4 + hi) ^ (orow & 7)) << 4));
          const bf16x8 af = *reinterpret_cast<const bf16x8*>(AshB + aoff);
#pragma unroll
          for (int nt = 0; nt < 4; ++nt)
            acc[mt][nt] = __builtin_amdgcn_mfma_f32_16x16x32_bf16(af, bfr[nt],
                                                                  acc[mt][nt], 0, 0, 0);
        }
      }

      if (cc < 3 && kk >= 1) writePiece(xb ^ 1, kk - 1, xhold);
      if (cc < 3 && kk == 8) writePiece(xb ^ 1, 8, xnew);
      if (has_next) writeA(ab ^ 1, areg);

      __syncthreads();
      ab ^= 1;
      xhold = xnew;
#pragma unroll
      for (int nt = 0; nt < 4; ++nt) wl[nt] = wln[nt];
    }
  }

  float* red = reinterpret_cast<float*>(&Ash[0][0]);
  red[tid] = 0.0f;
  __syncthreads();
#pragma unroll
  for (int mt = 0; mt < 8; ++mt) {
#pragma unroll
    for (int v = 0; v < 4; ++v) {
      const int o = wm * 128 + mt * 16 + hi * 4 + v;
      const float cb = convb[o];
      float s = 0.f, s2 = 0.f;
#pragma unroll
      for (int nt = 0; nt < 4; ++nt) {
        const int l = l0 + nbase + nt * 16;
        const float yv = acc[mt][nt][v] + cb;
        y[(((size_t)b * 256 + o) << 14) + l] = yv;
        s += yv; s2 += yv * yv;
      }
#pragma unroll
      for (int d = 1; d < 16; d <<= 1) { s += __shfl_xor(s, d); s2 += __shfl_xor(s2, d); }
      if (lo16 == 0) { atomicAdd(&red[o], s); atomicAdd(&red[o + 256], s2); }
    }
  }
  __syncthreads();
  atomicAdd(&sums[tid], red[tid]);
}

// ================= k_norm =================
template <int YBF>
__global__ void k_norm(const float* __restrict__ yf, const unsigned short* __restrict__ ybf,
                       float* __restrict__ out, const float* __restrict__ sums,
                       const float* __restrict__ gamma, const float* __restrict__ beta) {
  const size_t i0 = ((size_t)blockIdx.x * 256 + threadIdx.x) * 8;
  const int o = (int)((i0 >> 14) & 255);
  const float n = 131072.f;  // B*L
  const float mu = sums[o] / n;
  float var = sums[256 + o] / n - mu * mu;
  var = fmaxf(var, 0.f);
  const float sc = rsqrtf(var + 1e-5f) * gamma[o];
  const float bb = beta[o] - mu * sc;
  f32x4 v0, v1;
  if (YBF) {
    const u32x4 u = *reinterpret_cast<const u32x4*>(ybf + i0);
#pragma unroll
    for (int i = 0; i < 4; ++i) {
      const unsigned w = u[i];
      float a = bflo(w), c = bfhi(w);
      if (i < 2) { v0[2 * i] = a; v0[2 * i + 1] = c; }
      else       { v1[2 * (i - 2)] = a; v1[2 * (i - 2) + 1] = c; }
    }
  } else {
    v0 = *reinterpret_cast<const f32x4*>(yf + i0);
    v1 = *reinterpret_cast<const f32x4*>(yf + i0 + 4);
  }
#pragma unroll
  for (int i = 0; i < 4; ++i) {
    v0[i] = fmaxf(v0[i] * sc + bb, 0.f);
    v1[i] = fmaxf(v1[i] * sc + bb, 0.f);
  }
  *reinterpret_cast<f32x4*>(out + i0) = v0;
  *reinterpret_cast<f32x4*>(out + i0 + 4) = v1;
}

// ================= launch =================
extern "C" void kernel_launch(void* const* d_in, const int* in_sizes, int n_in,
                              void* d_out, int out_size, void* d_ws, size_t ws_size,
                              hipStream_t stream) {
  const float* x      = (const float*)d_in[0];
  const float* coords = (const float*)d_in[1];
  const float* conv_w = (const float*)d_in[2];
  const float* conv_b = (const float*)d_in[3];
  const float* gamma  = (const float*)d_in[4];
  const float* beta   = (const float*)d_in[5];
  float* out = (float*)d_out;

  // ws: stats 2KB | zeros 2KB | wbuf 4.72MB | AU 1.18MB (A_gl or A_r4 union) |
  //     xT 67.1MB | ybf 67.1MB   (need_big 73.0MB; need_ybf 140.1MB; r7 proved >=141.3MB)
  float* sums = (float*)d_ws;
  const unsigned short* zeros = (const unsigned short*)((char*)d_ws + 2048);
  float* wbuf = (float*)((char*)d_ws + 4096);
  unsigned short* AU  = (unsigned short*)((char*)d_ws + 4096 + (size_t)8 * 9 * LLEN * 4);
  unsigned short* xT  = AU + 589824;
  unsigned short* ybf = xT + 33554432;
  const size_t need_big = 4096 + (size_t)8 * 9 * LLEN * 4 + 1179648ull + 67108864ull;
  const size_t need_ybf = need_big + 67108864ull;
  const int big  = (ws_size >= need_big) ? 1 : 0;
  const int ybfp = (ws_size >= need_ybf) ? 1 : 0;

  k_prep<<<2304, 256, 0, stream>>>(conv_w, AU, sums, big);
  k_w<<<512, 256, 0, stream>>>(coords, wbuf);
  if (big) {
    k_xT<<<8192, 256, 0, stream>>>(x, xT);
    if (ybfp) {
      k_gemm16<1><<<512, 512, 0, stream>>>(xT, wbuf, AU, conv_b, zeros, out, ybf, sums);
      k_norm<1><<<16384, 256, 0, stream>>>(out, ybf, out, sums, gamma, beta);
    } else {
      k_gemm16<0><<<512, 512, 0, stream>>>(xT, wbuf, AU, conv_b, zeros, out, ybf, sums);
      k_norm<0><<<16384, 256, 0, stream>>>(out, ybf, out, sums, gamma, beta);
    }
  } else {
    k_gemm_fb<<<512, 512, 0, stream>>>(x, wbuf, AU, conv_b, out, sums);
    k_norm<0><<<16384, 256, 0, stream>>>(out, (const unsigned short*)out, out, sums, gamma, beta);
  }
}